// Round 15
// baseline (159.679 us; speedup 1.0000x reference)
//
#include <hip/hip_runtime.h>

#define KC   21      // num classes
#define BB   8       // batch
#define CC   256     // feat channels
#define HWP  65536   // 256*256 output pixels per image
#define SRC  4096    // 64*64 source pixels
#define NS   128     // chunks: (y-row, half) -> 32 source cells each
#define PC   32      // source cells per chunk
#define FST  257     // fs row stride: bank=(p+c)%32 -> <=2-way (free)

#define REP1 8       // k1 internal repeats (measurement round)
#define REP2 4       // k2 internal repeats (measurement round)

// d_ws layout (FIXED): L = B*HWP = 524288 BYTES [0, 524288) |
// partialw f32 @ float idx 131072 (byte 524288) | partial f32 after it.
// R9..R14 had WSF_PARTW=32768 (byte 131072): L's b>=2 images OVERLAPPED
// partialw/partial -> any second k2 execution read corrupted labels
// (R11/R14 failures). Restored to R8's disjoint layout.
#define WSF_PARTW 131072                     // float index (byte 524288)
#define WSF_PART  (WSF_PARTW + BB*NS*KC)     // float index of partial

// ---- k1: per-pixel argmax + gt-match -> label map (R13 body, x REP1) --------
__global__ __launch_bounds__(256, 2)
void k1_classify(const float* __restrict__ preds,
                 const int*   __restrict__ masks,
                 unsigned char* __restrict__ L,
                 float* __restrict__ out)
{
    int tid = threadIdx.x;
    if (blockIdx.x == 0) {
        float4* o4 = reinterpret_cast<float4*>(out);
#pragma unroll
        for (int i = 0; i < (KC * CC / 4 + 255) / 256; ++i) {
            int j = tid + i * 256;
            if (j < KC * CC / 4) o4[j] = make_float4(0.f, 0.f, 0.f, 0.f);
        }
    }

    int idx = blockIdx.x * 256 + tid;            // over B*HWP/4 = 131072
    int b   = idx >> 14;
    int hw4 = (idx & 16383) << 2;

#pragma unroll 1
    for (int rep = 0; rep < REP1; ++rep) {
        const float* pb = preds + (size_t)b * KC * HWP + hw4;
        float va[4][KC];
#pragma unroll
        for (int k = 0; k < KC; ++k) {
            float4 t = *reinterpret_cast<const float4*>(pb + (size_t)k * HWP);
            va[0][k] = t.x; va[1][k] = t.y; va[2][k] = t.z; va[3][k] = t.w;
        }

        int4 mm = *reinterpret_cast<const int4*>(masks + b * HWP + hw4);
        int mk[4] = { mm.x, mm.y, mm.z, mm.w };

        uchar4 r;
        unsigned char* rp = reinterpret_cast<unsigned char*>(&r);
#pragma unroll
        for (int j = 0; j < 4; ++j) {
            float best = va[j][0];
            int   bi   = 0;
#pragma unroll
            for (int k = 1; k < KC; ++k) {
                if (va[j][k] > best) { best = va[j][k]; bi = k; }  // first-index ties
            }
            rp[j] = (mk[j] == bi) ? (unsigned char)bi : (unsigned char)255;
        }
        *reinterpret_cast<uchar4*>(L + (size_t)b * HWP + hw4) = r;
        asm volatile("" ::: "memory");           // defeat cross-rep CSE
    }
}

// ---- k2: W gather + contraction (R13 body, x REP2; L now disjoint) ----------
__global__ __launch_bounds__(256, 4)
void k2_contract(const float* __restrict__ feats,      // [B][C][SRC]
                 const unsigned char* __restrict__ L,  // [B][256][256]
                 float* __restrict__ partial,          // [B][NS][K][C] f32
                 float* __restrict__ partialw)         // [B][NS][K]
{
    __shared__ float fs[PC * FST];    // 32.9 KB; reused as scr[21*256] later
    __shared__ float ws[KC * PC];     // 2.6 KB  (35.6 KB total -> 4 blocks/CU)
    int s = blockIdx.x, b = blockIdx.y;
    int tid = threadIdx.x;
    int y = s >> 1, x0c = (s & 1) * PC;
    int p0 = y * 64 + x0c;

#pragma unroll 1
    for (int rep = 0; rep < REP2; ++rep) {
        if (tid < KC * PC / 4)                            // 168 float4 zeros
            *reinterpret_cast<float4*>(ws + tid * 4) = make_float4(0.f, 0.f, 0.f, 0.f);
        __syncthreads();

        // stage feats[256 c][32 p] transposed -> fs[p][c]; 8 float4/thread
        {
            int q = tid & 7, c0 = tid >> 3;               // q: p-group, c0: 0..31
#pragma unroll
            for (int i = 0; i < 8; ++i) {
                int c = i * 32 + c0;
                float4 f4 = *reinterpret_cast<const float4*>(
                    feats + (size_t)(b * CC + c) * SRC + p0 + q * 4);
                fs[(q * 4 + 0) * FST + c] = f4.x;
                fs[(q * 4 + 1) * FST + c] = f4.y;
                fs[(q * 4 + 2) * FST + c] = f4.z;
                fs[(q * 4 + 3) * FST + c] = f4.w;
            }
        }

        // gather labels over influence zone: rows [4y-2,4y+5], cols [4x0c-2,+135]
        {
            int r = tid >> 5, cb = tid & 31;
            int h = 4 * y - 2 + r;
            if ((unsigned)h < 256u) {
                float sy = h * 0.25f - 0.375f;
                int   yt = (int)floorf(sy);
                float wy = sy - (float)yt;
                int ya = yt < 0 ? 0 : yt;
                int yb = yt + 1 > 63 ? 63 : yt + 1;
                float wyy = ((ya == y) ? (1.f - wy) : 0.f) + ((yb == y) ? wy : 0.f);
                if (wyy != 0.f) {
                    const unsigned char* Lrow = L + ((size_t)b << 16) + ((size_t)h << 8);
                    int wb0 = 4 * x0c - 2;
#pragma unroll
                    for (int j = 0; j < 5; ++j) {
                        int col = cb + j * 32;
                        int w = wb0 + col;
                        if (col < 136 && (unsigned)w < 256u) {
                            int k = Lrow[w];
                            if (k < KC) {
                                float sx = w * 0.25f - 0.375f;
                                int   xt = (int)floorf(sx);
                                float wx = sx - (float)xt;
                                int xa = xt < 0 ? 0 : xt;
                                int xb = xt + 1 > 63 ? 63 : xt + 1;
                                if (xa >= x0c && xa < x0c + PC)
                                    atomicAdd(&ws[k * PC + xa - x0c], wyy * (1.f - wx));  // dyadic-exact
                                if (xb >= x0c && xb < x0c + PC)
                                    atomicAdd(&ws[k * PC + xb - x0c], wyy * wx);
                            }
                        }
                    }
                }
            }
        }
        __syncthreads();

        int cp   = tid & 127;
        int psub = tid >> 7;                              // wave-uniform
        int pw   = psub * 16;

        float f0[16], f1[16];
#pragma unroll
        for (int p = 0; p < 16; ++p) {
            f0[p] = fs[(pw + p) * FST + cp];
            f1[p] = fs[(pw + p) * FST + cp + 128];
        }

        float swcnt = 0.f;
        if (tid < KC) {
#pragma unroll
            for (int p = 0; p < PC; ++p) swcnt += ws[tid * PC + ((p + tid) & (PC - 1))];
        }
        __syncthreads();   // fs reads done -> safe to overlay scr

        float acc0[KC], acc1[KC];
#pragma unroll
        for (int k = 0; k < KC; ++k) {
            const float* wk = ws + k * PC + pw;
            float a00 = 0.f, a01 = 0.f, a02 = 0.f, a03 = 0.f;
            float a10 = 0.f, a11 = 0.f, a12 = 0.f, a13 = 0.f;
#pragma unroll
            for (int q = 0; q < 4; ++q) {
                float4 w4 = *reinterpret_cast<const float4*>(wk + q * 4);  // uniform b128
                a00 += w4.x * f0[q * 4 + 0];
                a01 += w4.y * f0[q * 4 + 1];
                a02 += w4.z * f0[q * 4 + 2];
                a03 += w4.w * f0[q * 4 + 3];
                a10 += w4.x * f1[q * 4 + 0];
                a11 += w4.y * f1[q * 4 + 1];
                a12 += w4.z * f1[q * 4 + 2];
                a13 += w4.w * f1[q * 4 + 3];
            }
            acc0[k] = (a00 + a01) + (a02 + a03);
            acc1[k] = (a10 + a11) + (a12 + a13);
        }

        float* scr = fs;                                  // 21*256 = 5376 floats
        if (psub == 1) {
#pragma unroll
            for (int k = 0; k < KC; ++k) {
                scr[k * 256 + cp]       = acc0[k];
                scr[k * 256 + 128 + cp] = acc1[k];
            }
        }
        __syncthreads();
        if (psub == 0) {
            float* op = partial + ((size_t)(b * NS + s)) * KC * CC + cp;
#pragma unroll
            for (int k = 0; k < KC; ++k) {
                op[(size_t)k * CC]       = acc0[k] + scr[k * 256 + cp];
                op[(size_t)k * CC + 128] = acc1[k] + scr[k * 256 + 128 + cp];
            }
        }

        if (tid < KC)
            partialw[(size_t)(b * NS + s) * KC + tid] = swcnt;  // dyadic-exact

        __syncthreads();   // scr reads done before next rep overwrites fs
        asm volatile("" ::: "memory");
    }
}

// ---- k3: reduce chunks, derive exact counts, normalize (EXACT R13 version) --
__global__ __launch_bounds__(256)
void k3_finalize(const float* __restrict__ partial,   // [B][NS][K][C]
                 const float* __restrict__ partialw,  // [B][NS][K]
                 float* __restrict__ out)             // [K][C], zeroed by k1
{
    int k = blockIdx.x, b = blockIdx.y;
    int tid = threadIdx.x;

    const float* base = partial + ((size_t)(b * NS) * KC + k) * CC + tid;
    float acc = 0.f;
#pragma unroll 8
    for (int s = 0; s < NS; ++s) acc += base[(size_t)s * KC * CC];

    __shared__ float red[2];
    float v = 0.f;
    if (tid < NS) v = partialw[(size_t)(b * NS + tid) * KC + k];
#pragma unroll
    for (int off = 32; off; off >>= 1) v += __shfl_down(v, off);
    if (tid < NS && (tid & 63) == 0) red[tid >> 6] = v;
    __syncthreads();
    float cnt = red[0] + red[1];     // dyadic-exact pixel count

    atomicAdd(&out[k * CC + tid], acc / (8.f * (cnt + 1e-6f)));
}

extern "C" void kernel_launch(void* const* d_in, const int* in_sizes, int n_in,
                              void* d_out, int out_size, void* d_ws, size_t ws_size,
                              hipStream_t stream) {
    const float* feats = (const float*)d_in[0];   // [8,256,64,64]
    const float* preds = (const float*)d_in[1];   // [8,21,256,256]
    const int*   masks = (const int*)  d_in[2];   // [8,256,256]
    float* out = (float*)d_out;                   // [21,256]

    float* wsf = (float*)d_ws;
    unsigned char* L = (unsigned char*)d_ws;      // 524288 bytes, fully written by k1
    float* partialw = wsf + WSF_PARTW;            // byte 524288: DISJOINT from L
    float* partial  = wsf + WSF_PART;

    k1_classify<<<(BB * HWP / 4) / 256, 256, 0, stream>>>(preds, masks, L, out);
    k2_contract<<<dim3(NS, BB), 256, 0, stream>>>(feats, L, partial, partialw);
    k3_finalize<<<dim3(KC, BB), 256, 0, stream>>>(partial, partialw, out);
}

// Round 16
// 36.670 us; speedup vs baseline: 4.3545x; 4.3545x over previous
//
#include <hip/hip_runtime.h>

#define KC   21      // num classes
#define BB   8       // batch
#define CC   256     // feat channels
#define HWP  65536   // 256*256 output pixels per image
#define SRC  4096    // 64*64 source pixels
#define NS   128     // chunks: (y-row, half) -> 32 source cells each
#define PC   32      // source cells per chunk

// d_ws layout: L = 524288 BYTES [0, 524288) | partialw f32 @ byte 524288 | partial f32
#define WSF_PARTW 131072                     // float index (byte 524288)
#define WSF_PART  (WSF_PARTW + BB*NS*KC)     // float index of partial

// ---- k1: per-pixel argmax + gt-match -> label map (R13 body) ----------------
__global__ __launch_bounds__(256, 2)
void k1_classify(const float* __restrict__ preds,
                 const int*   __restrict__ masks,
                 unsigned char* __restrict__ L,
                 float* __restrict__ out)
{
    int tid = threadIdx.x;
    if (blockIdx.x == 0) {
        float4* o4 = reinterpret_cast<float4*>(out);
#pragma unroll
        for (int i = 0; i < (KC * CC / 4 + 255) / 256; ++i) {
            int j = tid + i * 256;
            if (j < KC * CC / 4) o4[j] = make_float4(0.f, 0.f, 0.f, 0.f);
        }
    }

    int idx = blockIdx.x * 256 + tid;            // over B*HWP/4 = 131072
    int b   = idx >> 14;
    int hw4 = (idx & 16383) << 2;

    const float* pb = preds + (size_t)b * KC * HWP + hw4;
    float va[4][KC];
#pragma unroll
    for (int k = 0; k < KC; ++k) {
        float4 t = *reinterpret_cast<const float4*>(pb + (size_t)k * HWP);
        va[0][k] = t.x; va[1][k] = t.y; va[2][k] = t.z; va[3][k] = t.w;
    }

    int4 mm = *reinterpret_cast<const int4*>(masks + b * HWP + hw4);
    int mk[4] = { mm.x, mm.y, mm.z, mm.w };

    uchar4 r;
    unsigned char* rp = reinterpret_cast<unsigned char*>(&r);
#pragma unroll
    for (int j = 0; j < 4; ++j) {
        float best = va[j][0];
        int   bi   = 0;
#pragma unroll
        for (int k = 1; k < KC; ++k) {
            if (va[j][k] > best) { best = va[j][k]; bi = k; }  // first-index ties
        }
        rp[j] = (mk[j] == bi) ? (unsigned char)bi : (unsigned char)255;
    }
    *reinterpret_cast<uchar4*>(L + (size_t)b * HWP + hw4) = r;
}

// ---- k2: no-LDS-staging contraction, 512 threads, full occupancy ------------
// R15 measurement: k2 = ~37 us = 95% of runtime at VALUBusy 16% / HBM 31% /
// Occ 43% -> latency-bound. This version: feats go global->reg directly
// (load latency hides under the L-gather), 512-thr blocks give 32 waves/CU
// (thread-slot max), 3 barriers instead of 5. LDS = ws + combine scratch only.
__global__ __launch_bounds__(512, 8)
void k2_contract(const float* __restrict__ feats,      // [B][C][SRC]
                 const unsigned char* __restrict__ L,  // [B][256][256]
                 float* __restrict__ partial,          // [B][NS][K][C] f32
                 float* __restrict__ partialw)         // [B][NS][K]
{
    __shared__ float ws[KC * PC];     // 2.6 KB, LDS-atomic gather target
    __shared__ float scr[KC * CC];    // 21.5 KB psub-combine scratch
    int s = blockIdx.x, b = blockIdx.y;
    int tid = threadIdx.x;            // 0..511
    int y = s >> 1, x0c = (s & 1) * PC;
    int p0 = y * 64 + x0c;

    int cp   = tid & 255;             // channel
    int psub = tid >> 8;              // wave-uniform p-half (waves 0-3 / 4-7)
    int pw   = psub * 16;

    if (tid < KC * PC / 4)            // zero ws: 168 float4
        *reinterpret_cast<float4*>(ws + tid * 4) = make_float4(0.f, 0.f, 0.f, 0.f);

    // feats: own row segment straight to registers (independent of ws; the
    // compiler issues these before the gather -> latency hidden under it)
    float f[16];
    {
        const float* frow = feats + (size_t)(b * CC + cp) * SRC + p0 + pw;
#pragma unroll
        for (int q = 0; q < 4; ++q) {
            float4 t = *reinterpret_cast<const float4*>(frow + q * 4);
            f[q * 4 + 0] = t.x; f[q * 4 + 1] = t.y;
            f[q * 4 + 2] = t.z; f[q * 4 + 3] = t.w;
        }
    }
    __syncthreads();                  // ws zeroed

    // gather labels over influence zone: rows [4y-2,4y+5] x cols [4x0c-2,+135]
    {
        int r = tid >> 6, cb = tid & 63;              // 8 rows x 64 threads
        int h = 4 * y - 2 + r;
        if ((unsigned)h < 256u) {
            float sy = h * 0.25f - 0.375f;
            int   yt = (int)floorf(sy);
            float wy = sy - (float)yt;
            int ya = yt < 0 ? 0 : yt;
            int yb = yt + 1 > 63 ? 63 : yt + 1;
            float wyy = ((ya == y) ? (1.f - wy) : 0.f) + ((yb == y) ? wy : 0.f);
            if (wyy != 0.f) {
                const unsigned char* Lrow = L + ((size_t)b << 16) + ((size_t)h << 8);
                int wb0 = 4 * x0c - 2;
#pragma unroll
                for (int j = 0; j < 3; ++j) {
                    int col = cb + j * 64;
                    int w = wb0 + col;
                    if (col < 136 && (unsigned)w < 256u) {
                        int k = Lrow[w];
                        if (k < KC) {
                            float sx = w * 0.25f - 0.375f;
                            int   xt = (int)floorf(sx);
                            float wx = sx - (float)xt;
                            int xa = xt < 0 ? 0 : xt;
                            int xb = xt + 1 > 63 ? 63 : xt + 1;
                            if (xa >= x0c && xa < x0c + PC)
                                atomicAdd(&ws[k * PC + xa - x0c], wyy * (1.f - wx));  // dyadic-exact
                            if (xb >= x0c && xb < x0c + PC)
                                atomicAdd(&ws[k * PC + xb - x0c], wyy * wx);
                        }
                    }
                }
            }
        }
    }
    __syncthreads();                  // ws final

    // exact per-chunk class-count contribution (rotated reads)
    float swcnt = 0.f;
    if (tid < KC) {
#pragma unroll
        for (int p = 0; p < PC; ++p) swcnt += ws[tid * PC + ((p + tid) & (PC - 1))];
    }

    float acc[KC];
#pragma unroll
    for (int k = 0; k < KC; ++k) {    // fully unrolled, static idx
        const float* wk = ws + k * PC + pw;
        float a0 = 0.f, a1 = 0.f, a2 = 0.f, a3 = 0.f;
#pragma unroll
        for (int q = 0; q < 4; ++q) {
            float4 w4 = *reinterpret_cast<const float4*>(wk + q * 4);  // uniform b128
            a0 += w4.x * f[q * 4 + 0];
            a1 += w4.y * f[q * 4 + 1];
            a2 += w4.z * f[q * 4 + 2];
            a3 += w4.w * f[q * 4 + 3];
        }
        acc[k] = (a0 + a1) + (a2 + a3);
    }

    // psub combine: psub1 parks in scr, psub0 adds and stores (coalesced 1KB/k)
    if (psub == 1) {
#pragma unroll
        for (int k = 0; k < KC; ++k) scr[k * CC + cp] = acc[k];
    }
    __syncthreads();
    if (psub == 0) {
        float* op = partial + ((size_t)(b * NS + s)) * KC * CC + cp;
#pragma unroll
        for (int k = 0; k < KC; ++k)
            op[(size_t)k * CC] = acc[k] + scr[k * CC + cp];
    }

    if (tid < KC)
        partialw[(size_t)(b * NS + s) * KC + tid] = swcnt;  // dyadic-exact
}

// ---- k3: reduce chunks, derive exact counts, normalize (unchanged) ----------
__global__ __launch_bounds__(256)
void k3_finalize(const float* __restrict__ partial,   // [B][NS][K][C]
                 const float* __restrict__ partialw,  // [B][NS][K]
                 float* __restrict__ out)             // [K][C], zeroed by k1
{
    int k = blockIdx.x, b = blockIdx.y;
    int tid = threadIdx.x;

    const float* base = partial + ((size_t)(b * NS) * KC + k) * CC + tid;
    float acc = 0.f;
#pragma unroll 8
    for (int s = 0; s < NS; ++s) acc += base[(size_t)s * KC * CC];

    __shared__ float red[2];
    float v = 0.f;
    if (tid < NS) v = partialw[(size_t)(b * NS + tid) * KC + k];
#pragma unroll
    for (int off = 32; off; off >>= 1) v += __shfl_down(v, off);
    if (tid < NS && (tid & 63) == 0) red[tid >> 6] = v;
    __syncthreads();
    float cnt = red[0] + red[1];     // dyadic-exact pixel count

    atomicAdd(&out[k * CC + tid], acc / (8.f * (cnt + 1e-6f)));
}

extern "C" void kernel_launch(void* const* d_in, const int* in_sizes, int n_in,
                              void* d_out, int out_size, void* d_ws, size_t ws_size,
                              hipStream_t stream) {
    const float* feats = (const float*)d_in[0];   // [8,256,64,64]
    const float* preds = (const float*)d_in[1];   // [8,21,256,256]
    const int*   masks = (const int*)  d_in[2];   // [8,256,256]
    float* out = (float*)d_out;                   // [21,256]

    float* wsf = (float*)d_ws;
    unsigned char* L = (unsigned char*)d_ws;      // 524288 bytes, fully written by k1
    float* partialw = wsf + WSF_PARTW;            // byte 524288: disjoint from L
    float* partial  = wsf + WSF_PART;

    k1_classify<<<(BB * HWP / 4) / 256, 256, 0, stream>>>(preds, masks, L, out);
    k2_contract<<<dim3(NS, BB), 512, 0, stream>>>(feats, L, partial, partialw);
    k3_finalize<<<dim3(KC, BB), 256, 0, stream>>>(partial, partialw, out);
}